// Round 2
// baseline (306.984 us; speedup 1.0000x reference)
//
#include <hip/hip_runtime.h>
#include <math.h>

#define D_DIM 16
#define N_PTS 100
#define VMIN_F (-5.0f)
#define INT_LEN_F (10.0f / 99.0f)
#define INV_INT_LEN_F (99.0f / 10.0f)

// ---------------------------------------------------------------------------
// Setup kernel (1 block, 256 threads):
//  - Gauss-Jordan inverse of (I - A) in fp64 (partial pivoting) -> Minv [16x16]
//  - w_tab[d][j]  = exp(p[d][j]) + 0.001            (16 x 101)
//  - db[d][i]     = b[d] + cumsum(INT_LEN*(exp(p[d][1..i])+0.001))  (16 x 100)
// ---------------------------------------------------------------------------
__global__ void scm_setup(const float* __restrict__ A,
                          const float* __restrict__ p,
                          const float* __restrict__ b,
                          float* __restrict__ Minv,
                          float* __restrict__ w_tab,
                          float* __restrict__ db) {
    __shared__ double aug[16][33];   // [I-A | I], padded
    __shared__ int piv;
    const int t = threadIdx.x;

    if (t < 16) {
        #pragma unroll
        for (int j = 0; j < 16; j++) {
            aug[t][j]      = (t == j ? 1.0 : 0.0) - (double)A[t * 16 + j];
            aug[t][16 + j] = (t == j ? 1.0 : 0.0);
        }
    }
    __syncthreads();

    for (int k = 0; k < 16; k++) {
        if (t == 0) {
            int pr = k; double best = fabs(aug[k][k]);
            for (int i = k + 1; i < 16; i++) {
                double v = fabs(aug[i][k]);
                if (v > best) { best = v; pr = i; }
            }
            piv = pr;
        }
        __syncthreads();
        const int pr = piv;
        if (pr != k && t < 32) {
            double tmp = aug[k][t]; aug[k][t] = aug[pr][t]; aug[pr][t] = tmp;
        }
        __syncthreads();
        const double pivval = aug[k][k];
        __syncthreads();
        if (t < 32) aug[k][t] = aug[k][t] / pivval;
        __syncthreads();
        if (t < 16 && t != k) {
            const double f = aug[t][k];
            #pragma unroll
            for (int j = 0; j < 32; j++) aug[t][j] -= f * aug[k][j];
        }
        __syncthreads();
    }

    if (t < 16) {
        #pragma unroll
        for (int j = 0; j < 16; j++) Minv[t * 16 + j] = (float)aug[t][16 + j];
    }

    for (int i = t; i < 16 * (N_PTS + 1); i += blockDim.x)
        w_tab[i] = expf(p[i]) + 0.001f;

    if (t < 16) {
        float acc = b[t];
        db[t * N_PTS + 0] = acc;
        for (int i = 1; i < N_PTS; i++) {
            acc += INT_LEN_F * (expf(p[t * (N_PTS + 1) + i]) + 0.001f);
            db[t * N_PTS + i] = acc;
        }
    }
}

// ---------------------------------------------------------------------------
// Main kernel: 256-row tile per block, fully coalesced global I/O via LDS.
//   - input staging:  4 x (1KB/wave contiguous float4 loads) -> sE
//     LDS layout: row stride = 5 float4 slots (20 floats, 4-float pad).
//     Both chunk-scatter writes and per-thread row reads hit the b128
//     structural minimum (8 lanes/bank-quad, balanced) -> conflict-free.
//   - compute: z = row @ Minv (LDS-broadcast), PWL via LDS tables
//   - output: thread writes its row back into sE, then coalesced store.
// ---------------------------------------------------------------------------
__global__ __launch_bounds__(256) void scm_main(
        const float* __restrict__ eps,
        const float* __restrict__ Minv,
        const float* __restrict__ w_tab,
        const float* __restrict__ db,
        float* __restrict__ out, int B) {
    __shared__ float sM[256];
    __shared__ float sW[16 * (N_PTS + 1)];
    __shared__ float sDB[16 * N_PTS];
    __shared__ float4 sE[256 * 5];   // 256 rows x 5 float4 slots (slot 4 = pad)

    const int t = threadIdx.x;

    for (int i = t; i < 256; i += 256) sM[i] = Minv[i];
    for (int i = t; i < 16 * (N_PTS + 1); i += 256) sW[i] = w_tab[i];
    for (int i = t; i < 16 * N_PTS; i += 256) sDB[i] = db[i];

    const int base = blockIdx.x * 256;
    const int rows = min(256, B - base);      // last tile may be partial

    // coalesced input staging: lane i <-> contiguous float4 i
    const float4* gin = (const float4*)(eps + (size_t)base * 16);
    #pragma unroll
    for (int q = 0; q < 4; q++) {
        const int f = q * 256 + t;            // global float4 index in tile
        if (f < rows * 4) {
            sE[(f >> 2) * 5 + (f & 3)] = gin[f];
        }
    }
    __syncthreads();

    if (t < rows) {
        const float4 c0 = sE[t * 5 + 0];
        const float4 c1 = sE[t * 5 + 1];
        const float4 c2 = sE[t * 5 + 2];
        const float4 c3 = sE[t * 5 + 3];
        const float e[16] = {c0.x, c0.y, c0.z, c0.w, c1.x, c1.y, c1.z, c1.w,
                             c2.x, c2.y, c2.z, c2.w, c3.x, c3.y, c3.z, c3.w};

        float z[16];
        #pragma unroll
        for (int d = 0; d < 16; d++) z[d] = 0.0f;

        #pragma unroll
        for (int k = 0; k < 16; k++) {
            const float ek = e[k];
            const float4 m0 = ((const float4*)sM)[k * 4 + 0];
            const float4 m1 = ((const float4*)sM)[k * 4 + 1];
            const float4 m2 = ((const float4*)sM)[k * 4 + 2];
            const float4 m3 = ((const float4*)sM)[k * 4 + 3];
            z[0]  = fmaf(ek, m0.x, z[0]);  z[1]  = fmaf(ek, m0.y, z[1]);
            z[2]  = fmaf(ek, m0.z, z[2]);  z[3]  = fmaf(ek, m0.w, z[3]);
            z[4]  = fmaf(ek, m1.x, z[4]);  z[5]  = fmaf(ek, m1.y, z[5]);
            z[6]  = fmaf(ek, m1.z, z[6]);  z[7]  = fmaf(ek, m1.w, z[7]);
            z[8]  = fmaf(ek, m2.x, z[8]);  z[9]  = fmaf(ek, m2.y, z[9]);
            z[10] = fmaf(ek, m2.z, z[10]); z[11] = fmaf(ek, m2.w, z[11]);
            z[12] = fmaf(ek, m3.x, z[12]); z[13] = fmaf(ek, m3.y, z[13]);
            z[14] = fmaf(ek, m3.z, z[14]); z[15] = fmaf(ek, m3.w, z[15]);
        }

        float o[16];
        #pragma unroll
        for (int d = 0; d < 16; d++) {
            const float zd = z[d];
            // searchsorted(points, z, 'right') on uniform grid; PWL is
            // continuous at knots so boundary rounding is harmless.
            const float tt = (zd - VMIN_F) * INV_INT_LEN_F;
            int idx = (int)floorf(tt) + 1;
            idx = min(max(idx, 0), N_PTS);
            const int sp_idx = max(idx - 1, 0);
            const float sp = VMIN_F + (float)sp_idx * INT_LEN_F;
            const float w  = sW[d * (N_PTS + 1) + idx];
            const float dbv = sDB[d * N_PTS + sp_idx];
            o[d] = fmaf(zd - sp, w, dbv);
        }

        // write own row back (only thread t touches row t between barriers)
        sE[t * 5 + 0] = make_float4(o[0],  o[1],  o[2],  o[3]);
        sE[t * 5 + 1] = make_float4(o[4],  o[5],  o[6],  o[7]);
        sE[t * 5 + 2] = make_float4(o[8],  o[9],  o[10], o[11]);
        sE[t * 5 + 3] = make_float4(o[12], o[13], o[14], o[15]);
    }
    __syncthreads();

    // coalesced output store
    float4* gout = (float4*)(out + (size_t)base * 16);
    #pragma unroll
    for (int q = 0; q < 4; q++) {
        const int f = q * 256 + t;
        if (f < rows * 4) {
            gout[f] = sE[(f >> 2) * 5 + (f & 3)];
        }
    }
}

extern "C" void kernel_launch(void* const* d_in, const int* in_sizes, int n_in,
                              void* d_out, int out_size, void* d_ws, size_t ws_size,
                              hipStream_t stream) {
    const float* eps = (const float*)d_in[0];
    const float* A   = (const float*)d_in[1];
    const float* p   = (const float*)d_in[2];
    const float* b   = (const float*)d_in[3];
    float* out = (float*)d_out;

    const int B = in_sizes[0] / D_DIM;

    // workspace layout: Minv[256] | w_tab[16*101] | db[16*100]
    float* ws    = (float*)d_ws;
    float* Minv  = ws;
    float* w_tab = ws + 256;
    float* db    = ws + 256 + 16 * (N_PTS + 1);

    scm_setup<<<1, 256, 0, stream>>>(A, p, b, Minv, w_tab, db);

    const int blocks = (B + 255) / 256;
    scm_main<<<blocks, 256, 0, stream>>>(eps, Minv, w_tab, db, out, B);
}

// Round 3
// 285.903 us; speedup vs baseline: 1.0737x; 1.0737x over previous
//
#include <hip/hip_runtime.h>
#include <math.h>

#define D_DIM 16
#define N_PTS 100
#define VMIN_F (-5.0f)
#define INT_LEN_F (10.0f / 99.0f)
#define INV_INT_LEN_F (99.0f / 10.0f)

// ---------------------------------------------------------------------------
// Setup kernel (1 block, 256 threads):
//  - Gauss-Jordan inverse of (I - A) in fp64 (partial pivoting) -> Minv [16x16]
//  - Combined PWL table Ctab[d][idx] = { w(idx), delta_bias(max(idx-1,0)) }
//    for idx in [0,100]; w = exp(p)+0.001, delta_bias = serial fp32 cumsum.
// ---------------------------------------------------------------------------
__global__ void scm_setup(const float* __restrict__ A,
                          const float* __restrict__ p,
                          const float* __restrict__ b,
                          float* __restrict__ Minv,
                          float2* __restrict__ Ctab) {
    __shared__ double aug[16][33];   // [I-A | I], padded
    __shared__ float db_s[16][N_PTS];
    __shared__ int piv;
    const int t = threadIdx.x;

    if (t < 16) {
        #pragma unroll
        for (int j = 0; j < 16; j++) {
            aug[t][j]      = (t == j ? 1.0 : 0.0) - (double)A[t * 16 + j];
            aug[t][16 + j] = (t == j ? 1.0 : 0.0);
        }
    }
    __syncthreads();

    for (int k = 0; k < 16; k++) {
        if (t == 0) {
            int pr = k; double best = fabs(aug[k][k]);
            for (int i = k + 1; i < 16; i++) {
                double v = fabs(aug[i][k]);
                if (v > best) { best = v; pr = i; }
            }
            piv = pr;
        }
        __syncthreads();
        const int pr = piv;
        if (pr != k && t < 32) {
            double tmp = aug[k][t]; aug[k][t] = aug[pr][t]; aug[pr][t] = tmp;
        }
        __syncthreads();
        const double pivval = aug[k][k];
        __syncthreads();
        if (t < 32) aug[k][t] = aug[k][t] / pivval;
        __syncthreads();
        if (t < 16 && t != k) {
            const double f = aug[t][k];
            #pragma unroll
            for (int j = 0; j < 32; j++) aug[t][j] -= f * aug[k][j];
        }
        __syncthreads();
    }

    if (t < 16) {
        #pragma unroll
        for (int j = 0; j < 16; j++) Minv[t * 16 + j] = (float)aug[t][16 + j];
    }

    // serial per-dim fp32 cumsum (matches reference jnp.cumsum ordering)
    if (t < 16) {
        float acc = b[t];
        db_s[t][0] = acc;
        for (int i = 1; i < N_PTS; i++) {
            acc += INT_LEN_F * (expf(p[t * (N_PTS + 1) + i]) + 0.001f);
            db_s[t][i] = acc;
        }
    }
    __syncthreads();

    // combined table: one float2 per (d, idx)
    for (int i = t; i < 16 * (N_PTS + 1); i += blockDim.x) {
        const int d   = i / (N_PTS + 1);
        const int idx = i - d * (N_PTS + 1);
        const int spi = idx > 0 ? idx - 1 : 0;
        float2 c;
        c.x = expf(p[i]) + 0.001f;   // w at idx
        c.y = db_s[d][spi];          // delta_bias at sp_idx
        Ctab[i] = c;
    }
}

// ---------------------------------------------------------------------------
// Main kernel: one thread per row.
//   - Minv read straight from global with wave-uniform indices -> the
//     compiler emits s_load (constant cache, scalar pipe), keeping the
//     16x16 matmul entirely off the LDS pipe. v_fmac takes the SGPR operand.
//   - PWL: single float2 LDS gather per dim (w and delta_bias fused).
//   - Global I/O: one 64B row per thread (one cache line), 4x float4.
// ---------------------------------------------------------------------------
__global__ __launch_bounds__(256) void scm_main(
        const float* __restrict__ eps,
        const float* __restrict__ Minv,
        const float2* __restrict__ Ctab,
        float* __restrict__ out, int B) {
    __shared__ float2 sC[16 * (N_PTS + 1)];

    const int t = threadIdx.x;
    const int row = blockIdx.x * 256 + t;

    // issue the row loads first so they overlap the LDS table fill
    float4 c0 = {0,0,0,0}, c1 = {0,0,0,0}, c2 = {0,0,0,0}, c3 = {0,0,0,0};
    if (row < B) {
        const float4* erow = (const float4*)(eps + (size_t)row * 16);
        c0 = erow[0]; c1 = erow[1]; c2 = erow[2]; c3 = erow[3];
    }

    for (int i = t; i < 16 * (N_PTS + 1); i += 256) sC[i] = Ctab[i];
    __syncthreads();

    if (row >= B) return;

    const float e[16] = {c0.x, c0.y, c0.z, c0.w, c1.x, c1.y, c1.z, c1.w,
                         c2.x, c2.y, c2.z, c2.w, c3.x, c3.y, c3.z, c3.w};

    float z[16];
    #pragma unroll
    for (int d = 0; d < 16; d++) z[d] = 0.0f;

    #pragma unroll
    for (int k = 0; k < 16; k++) {
        const float ek = e[k];
        #pragma unroll
        for (int d = 0; d < 16; d++) {
            z[d] = fmaf(ek, Minv[k * 16 + d], z[d]);   // Minv: uniform -> SGPR
        }
    }

    float o[16];
    #pragma unroll
    for (int d = 0; d < 16; d++) {
        const float zd = z[d];
        // searchsorted(points, z, 'right') on uniform grid; PWL is
        // continuous at knots so boundary rounding is harmless.
        const float tt = (zd - VMIN_F) * INV_INT_LEN_F;
        int idx = (int)floorf(tt) + 1;
        idx = min(max(idx, 0), N_PTS);
        const int sp_idx = max(idx - 1, 0);
        const float sp = VMIN_F + (float)sp_idx * INT_LEN_F;
        const float2 c = sC[d * (N_PTS + 1) + idx];
        o[d] = fmaf(zd - sp, c.x, c.y);
    }

    float4* orow = (float4*)(out + (size_t)row * 16);
    orow[0] = make_float4(o[0],  o[1],  o[2],  o[3]);
    orow[1] = make_float4(o[4],  o[5],  o[6],  o[7]);
    orow[2] = make_float4(o[8],  o[9],  o[10], o[11]);
    orow[3] = make_float4(o[12], o[13], o[14], o[15]);
}

extern "C" void kernel_launch(void* const* d_in, const int* in_sizes, int n_in,
                              void* d_out, int out_size, void* d_ws, size_t ws_size,
                              hipStream_t stream) {
    const float* eps = (const float*)d_in[0];
    const float* A   = (const float*)d_in[1];
    const float* p   = (const float*)d_in[2];
    const float* b   = (const float*)d_in[3];
    float* out = (float*)d_out;

    const int B = in_sizes[0] / D_DIM;

    // workspace layout: Minv[256 floats] | Ctab[16*101 float2] (8B-aligned)
    float*  ws   = (float*)d_ws;
    float*  Minv = ws;
    float2* Ctab = (float2*)(ws + 256);

    scm_setup<<<1, 256, 0, stream>>>(A, p, b, Minv, Ctab);

    const int blocks = (B + 255) / 256;
    scm_main<<<blocks, 256, 0, stream>>>(eps, Minv, Ctab, out, B);
}

// Round 4
// 270.633 us; speedup vs baseline: 1.1343x; 1.0564x over previous
//
#include <hip/hip_runtime.h>
#include <math.h>

#define D_DIM 16
#define N_PTS 100
#define VMIN_F (-5.0f)
#define INT_LEN_F (10.0f / 99.0f)
#define INV_INT_LEN_F (99.0f / 10.0f)

// ---------------------------------------------------------------------------
// Setup kernel (1 block, 256 threads):
//  - Gauss-Jordan inverse of (I - A) in fp64 (partial pivoting) -> Minv [16x16]
//  - Combined PWL table Ctab[d][idx] = { w(idx), delta_bias(max(idx-1,0)) }
//    for idx in [0,100]; w = exp(p)+0.001, delta_bias = serial fp32 cumsum.
// ---------------------------------------------------------------------------
__global__ void scm_setup(const float* __restrict__ A,
                          const float* __restrict__ p,
                          const float* __restrict__ b,
                          float* __restrict__ Minv,
                          float2* __restrict__ Ctab) {
    __shared__ double aug[16][33];   // [I-A | I], padded
    __shared__ float db_s[16][N_PTS];
    __shared__ int piv;
    const int t = threadIdx.x;

    if (t < 16) {
        #pragma unroll
        for (int j = 0; j < 16; j++) {
            aug[t][j]      = (t == j ? 1.0 : 0.0) - (double)A[t * 16 + j];
            aug[t][16 + j] = (t == j ? 1.0 : 0.0);
        }
    }
    __syncthreads();

    for (int k = 0; k < 16; k++) {
        if (t == 0) {
            int pr = k; double best = fabs(aug[k][k]);
            for (int i = k + 1; i < 16; i++) {
                double v = fabs(aug[i][k]);
                if (v > best) { best = v; pr = i; }
            }
            piv = pr;
        }
        __syncthreads();
        const int pr = piv;
        if (pr != k && t < 32) {
            double tmp = aug[k][t]; aug[k][t] = aug[pr][t]; aug[pr][t] = tmp;
        }
        __syncthreads();
        const double pivval = aug[k][k];
        __syncthreads();
        if (t < 32) aug[k][t] = aug[k][t] / pivval;
        __syncthreads();
        if (t < 16 && t != k) {
            const double f = aug[t][k];
            #pragma unroll
            for (int j = 0; j < 32; j++) aug[t][j] -= f * aug[k][j];
        }
        __syncthreads();
    }

    if (t < 16) {
        #pragma unroll
        for (int j = 0; j < 16; j++) Minv[t * 16 + j] = (float)aug[t][16 + j];
    }

    // serial per-dim fp32 cumsum (matches reference jnp.cumsum ordering)
    if (t < 16) {
        float acc = b[t];
        db_s[t][0] = acc;
        for (int i = 1; i < N_PTS; i++) {
            acc += INT_LEN_F * (expf(p[t * (N_PTS + 1) + i]) + 0.001f);
            db_s[t][i] = acc;
        }
    }
    __syncthreads();

    // combined table: one float2 per (d, idx)
    for (int i = t; i < 16 * (N_PTS + 1); i += blockDim.x) {
        const int d   = i / (N_PTS + 1);
        const int idx = i - d * (N_PTS + 1);
        const int spi = idx > 0 ? idx - 1 : 0;
        float2 c;
        c.x = expf(p[i]) + 0.001f;   // w at idx
        c.y = db_s[d][spi];          // delta_bias at sp_idx
        Ctab[i] = c;
    }
}

// DPP quad_perm broadcast: every lane in an aligned quad receives lane J's x.
// Pure VALU (no LDS pipe). All 4 quad lanes are always active together here
// (guard granularity = one row = one quad).
template <int J>
__device__ __forceinline__ float dpp_bcast(float x) {
    constexpr int ctrl = J | (J << 2) | (J << 4) | (J << 6);  // quad_perm
    int xi = __builtin_bit_cast(int, x);
    int r  = __builtin_amdgcn_mov_dpp(xi, ctrl, 0xf, 0xf, true);
    return __builtin_bit_cast(float, r);
}

// ---------------------------------------------------------------------------
// Main kernel: quad-cooperative. Lane l owns float4 #l (quarter q = l&3 of
// row l>>2) -> ALL global loads/stores fully coalesced (16 lines/instr vs 64
// for the old thread-per-row layout). Row reassembled in-register via 16
// v_mov_dpp quad_perm broadcasts. Each lane holds its 16x4 column block of
// Minv in VGPRs (loaded once, amortized by a grid-stride loop), so the
// matmul is 64 FMAs with no LDS/SGPR traffic. PWL = 4 float2 LDS gathers.
// ---------------------------------------------------------------------------
__global__ __launch_bounds__(256, 4) void scm_main(
        const float* __restrict__ eps,
        const float* __restrict__ Minv,
        const float2* __restrict__ Ctab,
        float* __restrict__ out, int B) {
    __shared__ float2 sC[16 * (N_PTS + 1)];

    const int t = threadIdx.x;
    const int q = t & 3;                    // quarter within row (constant/iter)

    for (int i = t; i < 16 * (N_PTS + 1); i += 256) sC[i] = Ctab[i];

    // Minv column block for this lane: Mcol[k] = Minv[k][4q .. 4q+3]
    float4 Mcol[16];
    #pragma unroll
    for (int k = 0; k < 16; k++)
        Mcol[k] = *(const float4*)(Minv + k * 16 + 4 * q);

    __syncthreads();

    const long total  = (long)B * 4;                  // float4 count
    const long stride = (long)gridDim.x * 256;
    long f4 = (long)blockIdx.x * 256 + t;

    const float4* in4  = (const float4*)eps;
    float4*       out4 = (float4*)out;

    float4 cur = make_float4(0.f, 0.f, 0.f, 0.f);
    if (f4 < total) cur = in4[f4];

    for (; f4 < total; f4 += stride) {
        // prefetch next chunk (overlaps this iteration's compute)
        const long nf4 = f4 + stride;
        float4 nxt = make_float4(0.f, 0.f, 0.f, 0.f);
        if (nf4 < total) nxt = in4[nf4];

        // reassemble full row e[16] from the quad's four quarters
        float e[16];
        e[0]  = dpp_bcast<0>(cur.x); e[1]  = dpp_bcast<0>(cur.y);
        e[2]  = dpp_bcast<0>(cur.z); e[3]  = dpp_bcast<0>(cur.w);
        e[4]  = dpp_bcast<1>(cur.x); e[5]  = dpp_bcast<1>(cur.y);
        e[6]  = dpp_bcast<1>(cur.z); e[7]  = dpp_bcast<1>(cur.w);
        e[8]  = dpp_bcast<2>(cur.x); e[9]  = dpp_bcast<2>(cur.y);
        e[10] = dpp_bcast<2>(cur.z); e[11] = dpp_bcast<2>(cur.w);
        e[12] = dpp_bcast<3>(cur.x); e[13] = dpp_bcast<3>(cur.y);
        e[14] = dpp_bcast<3>(cur.z); e[15] = dpp_bcast<3>(cur.w);

        // z[d] for this lane's four dims d = 4q+i
        float z0 = 0.f, z1 = 0.f, z2 = 0.f, z3 = 0.f;
        #pragma unroll
        for (int k = 0; k < 16; k++) {
            z0 = fmaf(e[k], Mcol[k].x, z0);
            z1 = fmaf(e[k], Mcol[k].y, z1);
            z2 = fmaf(e[k], Mcol[k].z, z2);
            z3 = fmaf(e[k], Mcol[k].w, z3);
        }

        // PWL per dim (uniform grid; continuous at knots)
        float zv[4] = {z0, z1, z2, z3};
        float o[4];
        #pragma unroll
        for (int i = 0; i < 4; i++) {
            const float zd = zv[i];
            const float tt = (zd - VMIN_F) * INV_INT_LEN_F;
            int idx = (int)floorf(tt) + 1;
            idx = min(max(idx, 0), N_PTS);
            const int sp_idx = max(idx - 1, 0);
            const float sp = VMIN_F + (float)sp_idx * INT_LEN_F;
            const float2 c = sC[(4 * q + i) * (N_PTS + 1) + idx];
            o[i] = fmaf(zd - sp, c.x, c.y);
        }

        out4[f4] = make_float4(o[0], o[1], o[2], o[3]);
        cur = nxt;
    }
}

extern "C" void kernel_launch(void* const* d_in, const int* in_sizes, int n_in,
                              void* d_out, int out_size, void* d_ws, size_t ws_size,
                              hipStream_t stream) {
    const float* eps = (const float*)d_in[0];
    const float* A   = (const float*)d_in[1];
    const float* p   = (const float*)d_in[2];
    const float* b   = (const float*)d_in[3];
    float* out = (float*)d_out;

    const int B = in_sizes[0] / D_DIM;

    // workspace layout: Minv[256 floats] | Ctab[16*101 float2] (8B-aligned)
    float*  ws   = (float*)d_ws;
    float*  Minv = ws;
    float2* Ctab = (float2*)(ws + 256);

    scm_setup<<<1, 256, 0, stream>>>(A, p, b, Minv, Ctab);

    long total_f4 = (long)B * 4;
    int blocks = (int)((total_f4 + 255) / 256);
    if (blocks > 2048) blocks = 2048;
    if (blocks < 1) blocks = 1;
    scm_main<<<blocks, 256, 0, stream>>>(eps, Minv, Ctab, out, B);
}